// Round 4
// baseline (593.934 us; speedup 1.0000x reference)
//
#include <hip/hip_runtime.h>
#include <hip/hip_bf16.h>
#include <stdint.h>

// EmotionTriadFusion on MI355X — Round 4: fp32 I/O (per reference dtypes),
// bf16 MFMA internals.
// B=16384, F=1024, E=28, A=2, T=128, H=4, HD=32.
//
// R0-R3 read inputs as bf16; reference setup_inputs() is float32. fp32 bits
// viewed as bf16 make ~1/256 of elements Inf/NaN (low mantissa halves) ->
// the persistent NaN. This build: inputs const float*, outputs float*.
//
// Pipeline:
//  ffb_convert: ff fp32 -> FFB bf16 (ws)
//  prep    : fold Wq_in*Wq, Wo*Wc, concat Wk|Wv; weights -> bf16 [N][K] in ws,
//            folded biases -> fp32 in ws
//  tokens  : softmax(28)->LN->(28->128)matmul->GELU x2 + affect -> TOK bf16
//  G1 qh   = FFB @ WqqT           M=16384 K=1024 N=128   -> QH bf16 (ws)
//  G2 kvh  = TOK @ [Wk|Wv]T       M=49152 K=128  N=256   -> summary slot (bf16 scratch)
//  attn    -> attw fp32 (d_out) + APRE bf16 (ws)
//  G3 ctx  = APRE @ WocT          M=16384 K=128  N=1024  -> refined slot (bf16 scratch)
//  G5 gh   = gelu([FFB|CTX]@Wg1T) M=16384 K=2048 N=1024  -> summary slot (bf16, kvh dead)
//  G6 pre  = ff_fp32 + sigmoid(gh@Wg2T)*ctx -> PRE bf16 (ws, aliases FFB: dead)
//  G4 summ = gelu(TOK @ WsT)      M=16384 K=384  N=1024  -> summary fp32 (final, gh dead)
//  ln      : LayerNorm(1024) PRE bf16 -> refined fp32 (final, ctx dead)
//
// ws peak = 62,199,296 B (~59.3 MB).

using bf16 = __hip_bfloat16;
typedef __bf16 bf16x8 __attribute__((ext_vector_type(8)));
typedef float f32x4 __attribute__((ext_vector_type(4)));

__device__ __forceinline__ float b2f(bf16 x) { return __bfloat162float(x); }
__device__ __forceinline__ bf16 f2b(float x) { return __float2bfloat16(x); }
__device__ __forceinline__ float gelu_f(float x) {
  return 0.5f * x * (1.0f + erff(x * 0.70710678118654752f));
}

__device__ __forceinline__ void async_ld16(const void* g, void* l) {
  using GP = const __attribute__((address_space(1))) uint32_t*;
  using LP = __attribute__((address_space(3))) uint32_t*;
  __builtin_amdgcn_global_load_lds((GP)g, (LP)l, 16, 0, 0);
}

// ---------------------------------------------------------------------------
// ff fp32 -> bf16, 4 elems/thread.
// ---------------------------------------------------------------------------
__global__ void ffb_convert(const float* __restrict__ src, bf16* __restrict__ dst) {
  size_t i = ((size_t)blockIdx.x * 256 + threadIdx.x) * 4;
  float4 v = *reinterpret_cast<const float4*>(src + i);
  ushort4 o;
  o.x = __builtin_bit_cast(unsigned short, f2b(v.x));
  o.y = __builtin_bit_cast(unsigned short, f2b(v.y));
  o.z = __builtin_bit_cast(unsigned short, f2b(v.z));
  o.w = __builtin_bit_cast(unsigned short, f2b(v.w));
  *reinterpret_cast<ushort4*>(dst + i) = o;
}

// ---------------------------------------------------------------------------
// Tiled MFMA GEMM: C[M,N] = act(A[M,K] @ B[K,N] + bias), B as bf16 BT[N][K].
// A operands are bf16 (our own activations). bias fp32.
// Tile 128x128, BK=64, 4 waves 2x2, wave 64x64 via 4x4 of 16x16x32.
// A split at ksplit between A0/A1 (both bf16).
// EPI: 0 bias; 1 bias+GELU; 2 out = ff_fp32 + sigmoid(bias+acc)*ctx_bf16.
// OutT: float (final outputs) or bf16 (scratch).
// ---------------------------------------------------------------------------
template <int EPI, typename OutT>
__launch_bounds__(256)
__global__ void gemm128(const bf16* A0, const bf16* A1, int ksplit, int lda0, int lda1,
                        const bf16* __restrict__ BT, int K,
                        const float* __restrict__ bias,
                        OutT* out, int ldo,
                        const float* ffp, const bf16* ctxp, int ldfc)
{
  __shared__ uint16_t smA[128 * 64];
  __shared__ uint16_t smB[128 * 64];
  const int tid = threadIdx.x;
  const int w = tid >> 6;
  const int l = tid & 63;
  const int m0 = blockIdx.x * 128;
  const int n0 = blockIdx.y * 128;
  const int wr = w >> 1, wc = w & 1;
  const int lrow = l & 15, lquad = l >> 4;
  const int rb = w * 8 + (l >> 3);  // staging row within 32-row group
  const int cpos = l & 7;           // staging 16B-chunk position

  const f32x4 vzero = {0.f, 0.f, 0.f, 0.f};
  f32x4 acc[4][4];
#pragma unroll
  for (int i = 0; i < 4; i++)
#pragma unroll
    for (int j = 0; j < 4; j++) acc[i][j] = vzero;

  for (int k0 = 0; k0 < K; k0 += 64) {
    __syncthreads();
    // LDS (row, c) holds global chunk c ^ (row&7); lane lands at wave-uniform
    // base + lane*16 (global_load_lds constraint).
#pragma unroll
    for (int i = 0; i < 4; i++) {
      int row = i * 32 + rb;
      int cg = cpos ^ (row & 7);
      int kcol = k0 + cg * 8;
      const bf16* gp = (kcol < ksplit)
                           ? (A0 + (size_t)(m0 + row) * lda0 + kcol)
                           : (A1 + (size_t)(m0 + row) * lda1 + (kcol - ksplit));
      async_ld16(gp, &smA[(i * 32 + w * 8) * 64]);
      const bf16* gq = BT + (size_t)(n0 + row) * K + k0 + cg * 8;
      async_ld16(gq, &smB[(i * 32 + w * 8) * 64]);
    }
    __syncthreads();
#pragma unroll
    for (int kk = 0; kk < 2; kk++) {
      bf16x8 af[4], bfr[4];
      const int cc = kk * 4 + lquad;
#pragma unroll
      for (int mi = 0; mi < 4; mi++) {
        int r = wr * 64 + mi * 16 + lrow;
        af[mi] = *(const bf16x8*)&smA[r * 64 + ((cc ^ (r & 7)) << 3)];
      }
#pragma unroll
      for (int ni = 0; ni < 4; ni++) {
        int r = wc * 64 + ni * 16 + lrow;
        bfr[ni] = *(const bf16x8*)&smB[r * 64 + ((cc ^ (r & 7)) << 3)];
      }
#pragma unroll
      for (int mi = 0; mi < 4; mi++)
#pragma unroll
        for (int ni = 0; ni < 4; ni++)
          acc[mi][ni] =
              __builtin_amdgcn_mfma_f32_16x16x32_bf16(af[mi], bfr[ni], acc[mi][ni], 0, 0, 0);
    }
  }

  // epilogue: C/D layout col=lane&15, row=(lane>>4)*4+reg
#pragma unroll
  for (int mi = 0; mi < 4; mi++) {
#pragma unroll
    for (int ni = 0; ni < 4; ni++) {
#pragma unroll
      for (int r = 0; r < 4; r++) {
        int row = m0 + wr * 64 + mi * 16 + lquad * 4 + r;
        int col = n0 + wc * 64 + ni * 16 + lrow;
        float v = acc[mi][ni][r] + bias[col];
        if (EPI == 1) v = gelu_f(v);
        if (EPI == 2) {
          float gate = 1.f / (1.f + expf(-v));
          size_t fo = (size_t)row * ldfc + col;
          v = ffp[fo] + gate * b2f(ctxp[fo]);
        }
        if constexpr (__is_same(OutT, float))
          out[(size_t)row * ldo + col] = v;
        else
          out[(size_t)row * ldo + col] = f2b(v);
      }
    }
  }
}

// ---------------------------------------------------------------------------
// Prep: fp32 weights -> bf16 transposed/folded weights + fp32 folded biases.
// ---------------------------------------------------------------------------
__global__ void prep_kernel(
    const float* __restrict__ Wq_in, const float* __restrict__ bq_in,
    const float* __restrict__ Wq, const float* __restrict__ bq,
    const float* __restrict__ Wk, const float* __restrict__ bk,
    const float* __restrict__ Wv, const float* __restrict__ bv,
    const float* __restrict__ Wo, const float* __restrict__ bo,
    const float* __restrict__ Wc, const float* __restrict__ bc,
    const float* __restrict__ Ws, const float* __restrict__ Wg1,
    const float* __restrict__ Wg2,
    bf16* WKVT, float* BKV, bf16* WQQT, float* BQQ, bf16* WOCT, float* BOC,
    bf16* WST, bf16* WG1T, bf16* WG2T)
{
  int idx = blockIdx.x * 256 + threadIdx.x;
  if (idx < 32768) {  // WKVT[n][k] = (n<128 ? Wk : Wv)[k][n%128]
    int n = idx >> 7, k = idx & 127;
    WKVT[idx] = f2b((n < 128) ? Wk[k * 128 + n] : Wv[k * 128 + (n - 128)]);
    return;
  }
  idx -= 32768;
  if (idx < 256) { BKV[idx] = (idx < 128) ? bk[idx] : bv[idx - 128]; return; }
  idx -= 256;
  if (idx < 131072) {  // WQQT[t][f] = sum_u Wq_in[f][u] * Wq[u][t]
    int t = idx >> 10, f = idx & 1023;
    float s = 0.f;
    for (int u = 0; u < 128; u++) s += Wq_in[f * 128 + u] * Wq[u * 128 + t];
    WQQT[idx] = f2b(s);
    return;
  }
  idx -= 131072;
  if (idx < 128) {  // BQQ[t] = bq_in @ Wq[:,t] + bq[t]
    float s = bq[idx];
    for (int u = 0; u < 128; u++) s += bq_in[u] * Wq[u * 128 + idx];
    BQQ[idx] = s;
    return;
  }
  idx -= 128;
  if (idx < 131072) {  // WOCT[f][d] = sum_t Wo[d][t] * Wc[t][f]
    int f = idx >> 7, d = idx & 127;
    float s = 0.f;
    for (int t = 0; t < 128; t++) s += Wo[d * 128 + t] * Wc[t * 1024 + f];
    WOCT[idx] = f2b(s);
    return;
  }
  idx -= 131072;
  if (idx < 1024) {  // BOC[f] = bo @ Wc[:,f] + bc[f]
    float s = bc[idx];
    for (int t = 0; t < 128; t++) s += bo[t] * Wc[t * 1024 + idx];
    BOC[idx] = s;
    return;
  }
  idx -= 1024;
  if (idx < 393216) { int f = idx / 384, j = idx % 384; WST[idx] = f2b(Ws[j * 1024 + f]); return; }
  idx -= 393216;
  if (idx < 2097152) { int f = idx >> 11, j = idx & 2047; WG1T[idx] = f2b(Wg1[j * 1024 + f]); return; }
  idx -= 2097152;
  if (idx < 1048576) { int f = idx >> 10, j = idx & 1023; WG2T[idx] = f2b(Wg2[j * 1024 + f]); return; }
}

// ---------------------------------------------------------------------------
// Tokens: fp32 in, bf16 TOK out. One block (128 thr) per row.
// ---------------------------------------------------------------------------
__device__ __forceinline__ void emb28(const float* __restrict__ logits,
                                      const float* __restrict__ g,
                                      const float* __restrict__ bb,
                                      const float* __restrict__ W,
                                      const float* __restrict__ wb,
                                      bf16* __restrict__ out, int t,
                                      float* sv, float* sp)
{
  if (t < 28) sv[t] = logits[t];
  __syncthreads();
  float mx = sv[0];
#pragma unroll
  for (int e = 1; e < 28; e++) mx = fmaxf(mx, sv[e]);
  if (t < 28) sp[t] = expf(sv[t] - mx);
  __syncthreads();
  float sum = 0.f;
#pragma unroll
  for (int e = 0; e < 28; e++) sum += sp[e];
  float inv = 1.f / sum;
  float sp2 = 0.f;
#pragma unroll
  for (int e = 0; e < 28; e++) { float p = sp[e] * inv; sp2 += p * p; }
  const float mean = 1.f / 28.f;  // softmax sums to 1
  float var = sp2 * (1.f / 28.f) - mean * mean;
  float rstd = rsqrtf(var + 1e-5f);
  __syncthreads();
  if (t < 28) sp[t] = (sp[t] * inv - mean) * rstd * g[t] + bb[t];
  __syncthreads();
  float acc = wb[t];
#pragma unroll
  for (int e = 0; e < 28; e++) acc += sp[e] * W[e * 128 + t];
  out[t] = f2b(gelu_f(acc));
  __syncthreads();
}

__global__ void tokens_kernel(
    const float* __restrict__ exl, const float* __restrict__ iml, const float* __restrict__ affv,
    const float* __restrict__ geg, const float* __restrict__ geb,
    const float* __restrict__ Wex, const float* __restrict__ bex,
    const float* __restrict__ gig, const float* __restrict__ gib,
    const float* __restrict__ Wim, const float* __restrict__ bim,
    const float* __restrict__ gag, const float* __restrict__ gab,
    const float* __restrict__ Waf, const float* __restrict__ baf,
    bf16* __restrict__ tokens)
{
  __shared__ float sv[28], sp[28];
  const int b = blockIdx.x, t = threadIdx.x;
  bf16* trow = tokens + (size_t)b * 384;
  emb28(exl + (size_t)b * 28, geg, geb, Wex, bex, trow, t, sv, sp);
  emb28(iml + (size_t)b * 28, gig, gib, Wim, bim, trow + 128, t, sv, sp);
  // affect: LN over 2 values
  float a0 = affv[(size_t)b * 2 + 0];
  float a1 = affv[(size_t)b * 2 + 1];
  float m = 0.5f * (a0 + a1);
  float d0 = a0 - m, d1 = a1 - m;
  float var = 0.5f * (d0 * d0 + d1 * d1);
  float rstd = rsqrtf(var + 1e-5f);
  float l0 = d0 * rstd * gag[0] + gab[0];
  float l1 = d1 * rstd * gag[1] + gab[1];
  float acc = baf[t] + l0 * Waf[t] + l1 * Waf[128 + t];
  trow[256 + t] = f2b(gelu_f(acc));
}

// ---------------------------------------------------------------------------
// Attention: per row, 4 heads x 3 keys; head = t/32, dim = t%32.
// qh/kvh bf16; apre bf16; attw fp32 (final output).
// ---------------------------------------------------------------------------
__global__ void attn_kernel(const bf16* __restrict__ qh, const bf16* __restrict__ kvh,
                            bf16* __restrict__ apre, float* __restrict__ attw)
{
  const int b = blockIdx.x, t = threadIdx.x;  // 128 threads
  float q = b2f(qh[(size_t)b * 128 + t]);
  const bf16* kv = kvh + (size_t)b * 3 * 256;
  float s[3], v[3];
#pragma unroll
  for (int i = 0; i < 3; i++) {
    float k = b2f(kv[i * 256 + t]);
    v[i] = b2f(kv[i * 256 + 128 + t]);
    float r = q * k;
#pragma unroll
    for (int off = 16; off > 0; off >>= 1) r += __shfl_down(r, off, 32);
    r = __shfl(r, 0, 32);
    s[i] = r * 0.17677669529663687f;  // 1/sqrt(32)
  }
  float mx = fmaxf(s[0], fmaxf(s[1], s[2]));
  float e0 = expf(s[0] - mx), e1 = expf(s[1] - mx), e2 = expf(s[2] - mx);
  float inv = 1.f / (e0 + e1 + e2);
  float w0 = e0 * inv, w1 = e1 * inv, w2 = e2 * inv;
  apre[(size_t)b * 128 + t] = f2b(w0 * v[0] + w1 * v[1] + w2 * v[2]);
  __shared__ float aw[4][3];
  if ((t & 31) == 0) { int h = t >> 5; aw[h][0] = w0; aw[h][1] = w1; aw[h][2] = w2; }
  __syncthreads();
  if (t < 3)
    attw[(size_t)b * 3 + t] = 0.25f * (aw[0][t] + aw[1][t] + aw[2][t] + aw[3][t]);
}

// ---------------------------------------------------------------------------
// Output LayerNorm over 1024: bf16 in (PRE), fp32 out. One block/row.
// ---------------------------------------------------------------------------
__global__ void ln_out_kernel(const bf16* __restrict__ x, const float* __restrict__ g,
                              const float* __restrict__ bb, float* __restrict__ out)
{
  const int row = blockIdx.x, t = threadIdx.x;
  const bf16* xr = x + (size_t)row * 1024;
  ushort4 u = *reinterpret_cast<const ushort4*>(xr + t * 4);
  float v0 = __uint_as_float((uint32_t)u.x << 16);
  float v1 = __uint_as_float((uint32_t)u.y << 16);
  float v2 = __uint_as_float((uint32_t)u.z << 16);
  float v3 = __uint_as_float((uint32_t)u.w << 16);
  float s = v0 + v1 + v2 + v3;
  float s2 = v0 * v0 + v1 * v1 + v2 * v2 + v3 * v3;
#pragma unroll
  for (int off = 32; off > 0; off >>= 1) {
    s += __shfl_down(s, off, 64);
    s2 += __shfl_down(s2, off, 64);
  }
  __shared__ float ls[4], ls2[4];
  const int w = t >> 6;
  if ((t & 63) == 0) { ls[w] = s; ls2[w] = s2; }
  __syncthreads();
  float S = ls[0] + ls[1] + ls[2] + ls[3];
  float S2 = ls2[0] + ls2[1] + ls2[2] + ls2[3];
  float mean = S * (1.f / 1024.f);
  float var = S2 * (1.f / 1024.f) - mean * mean;
  float rstd = rsqrtf(var + 1e-5f);
  const int c = t * 4;
  float4 o;
  o.x = (v0 - mean) * rstd * g[c + 0] + bb[c + 0];
  o.y = (v1 - mean) * rstd * g[c + 1] + bb[c + 1];
  o.z = (v2 - mean) * rstd * g[c + 2] + bb[c + 2];
  o.w = (v3 - mean) * rstd * g[c + 3] + bb[c + 3];
  *reinterpret_cast<float4*>(out + (size_t)row * 1024 + c) = o;
}

// ---------------------------------------------------------------------------
extern "C" void kernel_launch(void* const* d_in, const int* in_sizes, int n_in,
                              void* d_out, int out_size, void* d_ws, size_t ws_size,
                              hipStream_t stream)
{
  const float* ff   = (const float*)d_in[0];
  const float* exl  = (const float*)d_in[1];
  const float* iml  = (const float*)d_in[2];
  const float* affv = (const float*)d_in[3];
  const float* geg = (const float*)d_in[4],  *geb = (const float*)d_in[5];
  const float* Wex = (const float*)d_in[6],  *bex = (const float*)d_in[7];
  const float* gig = (const float*)d_in[8],  *gib = (const float*)d_in[9];
  const float* Wim = (const float*)d_in[10], *bim = (const float*)d_in[11];
  const float* gag = (const float*)d_in[12], *gab = (const float*)d_in[13];
  const float* Waf = (const float*)d_in[14], *baf = (const float*)d_in[15];
  const float* Wq_in = (const float*)d_in[16], *bq_in = (const float*)d_in[17];
  const float* Wq = (const float*)d_in[18], *bq = (const float*)d_in[19];
  const float* Wk = (const float*)d_in[20], *bk = (const float*)d_in[21];
  const float* Wv = (const float*)d_in[22], *bv = (const float*)d_in[23];
  const float* Wo = (const float*)d_in[24], *bo = (const float*)d_in[25];
  const float* Wc = (const float*)d_in[26], *bc = (const float*)d_in[27];
  const float* Ws = (const float*)d_in[28], *bs = (const float*)d_in[29];
  const float* Wg1 = (const float*)d_in[30], *bg1 = (const float*)d_in[31];
  const float* Wg2 = (const float*)d_in[32], *bg2 = (const float*)d_in[33];
  const float* lng = (const float*)d_in[34], *lnb = (const float*)d_in[35];

  // workspace layout (bytes); peak = 62,199,296 (~59.3 MB)
  char* ws = (char*)d_ws;
  bf16*  WKVT = (bf16*)(ws + 0);         //  32768 el bf16
  float* BKV  = (float*)(ws + 65536);    //    256 el f32
  bf16*  WQQT = (bf16*)(ws + 66560);     // 131072 el bf16
  float* BQQ  = (float*)(ws + 328704);   //    128 el f32
  bf16*  WOCT = (bf16*)(ws + 329216);    // 131072 el bf16
  float* BOC  = (float*)(ws + 591360);   //   1024 el f32
  bf16*  WST  = (bf16*)(ws + 595456);    // 393216 el bf16
  bf16*  WG1T = (bf16*)(ws + 1381888);   // 2097152 el bf16
  bf16*  WG2T = (bf16*)(ws + 5576192);   // 1048576 el bf16
  bf16*  FFB  = (bf16*)(ws + 7673344);   // B*1024 (live: convert..G5)
  bf16*  PRE  = (bf16*)(ws + 7673344);   // B*1024, aliases FFB (live: G6..ln)
  bf16*  TOK  = (bf16*)(ws + 41227776);  // B*384  (live: tokens..G4)
  bf16*  QH   = (bf16*)(ws + 53810688);  // B*128  (live: G1..attn)
  bf16*  APRE = (bf16*)(ws + 58004992);  // B*128  (live: attn..G3)

  float* outp = (float*)d_out;
  float* out_refined = outp;             // B*1024 f32; hosts CTX bf16 G3..G6
  float* out_attw    = outp + 16777216;  // B*3 f32
  float* out_summary = outp + 16826368;  // B*1024 f32; hosts KVH bf16 G2..attn, GATEH bf16 G5..G6
  bf16* CTX   = (bf16*)out_refined;
  bf16* KVH   = (bf16*)out_summary;
  bf16* GATEH = (bf16*)out_summary;

  ffb_convert<<<16384, 256, 0, stream>>>(ff, FFB);
  prep_kernel<<<14982, 256, 0, stream>>>(Wq_in, bq_in, Wq, bq, Wk, bk, Wv, bv,
                                         Wo, bo, Wc, bc, Ws, Wg1, Wg2,
                                         WKVT, BKV, WQQT, BQQ, WOCT, BOC,
                                         WST, WG1T, WG2T);
  tokens_kernel<<<16384, 128, 0, stream>>>(exl, iml, affv, geg, geb, Wex, bex,
                                           gig, gib, Wim, bim, gag, gab, Waf, baf, TOK);
  // G1: qh = FFB @ WqqT + bqq  (M=16384, K=1024, N=128)
  gemm128<0, bf16><<<dim3(128, 1), 256, 0, stream>>>(FFB, FFB, 1024, 1024, 1024, WQQT, 1024,
                                                     BQQ, QH, 128, nullptr, nullptr, 0);
  // G2: kvh = TOK @ [Wk|Wv]T  (M=49152, K=128, N=256) -> summary slot
  gemm128<0, bf16><<<dim3(384, 2), 256, 0, stream>>>(TOK, TOK, 128, 128, 128, WKVT, 128,
                                                     BKV, KVH, 256, nullptr, nullptr, 0);
  attn_kernel<<<16384, 128, 0, stream>>>(QH, KVH, APRE, out_attw);
  // G3: ctx = APRE @ WocT + boc  (M=16384, K=128, N=1024) -> refined slot (bf16)
  gemm128<0, bf16><<<dim3(128, 8), 256, 0, stream>>>(APRE, APRE, 128, 128, 128, WOCT, 128,
                                                     BOC, CTX, 1024, nullptr, nullptr, 0);
  // G5: gate_h = gelu([FFB|CTX] @ Wg1T + bg1)  (K=2048) -> summary slot (kvh dead)
  gemm128<1, bf16><<<dim3(128, 8), 256, 0, stream>>>(FFB, CTX, 1024, 1024, 1024, WG1T, 2048,
                                                     bg1, GATEH, 1024, nullptr, nullptr, 0);
  // G6: pre = ff_fp32 + sigmoid(gate_h @ Wg2T + bg2) * ctx -> PRE (ws; FFB dead)
  gemm128<2, bf16><<<dim3(128, 8), 256, 0, stream>>>(GATEH, GATEH, 1024, 1024, 1024, WG2T, 1024,
                                                     bg2, PRE, 1024, ff, CTX, 1024);
  // G4: summary = gelu(TOK @ WsT + bs)  (K=384) -> summary fp32 final (gateh dead)
  gemm128<1, float><<<dim3(128, 8), 256, 0, stream>>>(TOK, TOK, 384, 384, 384, WST, 384,
                                                      bs, out_summary, 1024, nullptr, nullptr, 0);
  // final LN: PRE bf16 -> refined fp32 (ctx dead)
  ln_out_kernel<<<16384, 256, 0, stream>>>(PRE, lng, lnb, out_refined);
}

// Round 5
// 557.338 us; speedup vs baseline: 1.0657x; 1.0657x over previous
//
#include <hip/hip_runtime.h>
#include <hip/hip_bf16.h>
#include <stdint.h>

// EmotionTriadFusion on MI355X — Round 5: fast transcendentals + tiled-M GEMM.
// B=16384, F=1024, E=28, A=2, T=128, H=4, HD=32. fp32 I/O, bf16 MFMA internals.
//
// R4 passed (594 us, absmax 0.031). Counters: G5 (K=2048) = 109 us at
// MfmaUtil 26%, VALUBusy 50% — epilogue erff (~40+ VALU ops x64/thread) is
// ~1/3 of G5 and dominates short-K GEMMs. This round: tanh-GELU via __expf,
// __expf sigmoid/softmax, G6 residual from bf16 FFB (-33.5MB fetch),
// 64-row-tile GEMM for G1 (grid 128 -> 256 blocks).
//
// Pipeline:
//  ffb_convert: ff fp32 -> FFB bf16 (ws)
//  prep    : fold Wq_in*Wq, Wo*Wc, concat Wk|Wv -> bf16 [N][K] + fp32 biases
//  tokens  : softmax(28)->LN->(28->128)matmul->GELU x2 + affect -> TOK bf16
//  G1 qh   = FFB @ WqqT           M=16384 K=1024 N=128   -> QH bf16 (MT=64)
//  G2 kvh  = TOK @ [Wk|Wv]T       M=49152 K=128  N=256   -> summary slot
//  attn    -> attw fp32 (d_out) + APRE bf16 (ws)
//  G3 ctx  = APRE @ WocT          M=16384 K=128  N=1024  -> refined slot (bf16)
//  G5 gh   = gelu([FFB|CTX]@Wg1T) M=16384 K=2048 N=1024  -> summary slot
//  G6 pre  = FFB + sigmoid(gh@Wg2T)*ctx -> PRE bf16 (aliases FFB, elem-wise safe)
//  G4 summ = gelu(TOK @ WsT)      M=16384 K=384  N=1024  -> summary fp32 (final)
//  ln      : LayerNorm(1024) PRE bf16 -> refined fp32 (final)
//
// ws peak = 62,199,296 B (~59.3 MB).

using bf16 = __hip_bfloat16;
typedef __bf16 bf16x8 __attribute__((ext_vector_type(8)));
typedef float f32x4 __attribute__((ext_vector_type(4)));

__device__ __forceinline__ float b2f(bf16 x) { return __bfloat162float(x); }
__device__ __forceinline__ bf16 f2b(float x) { return __float2bfloat16(x); }

// tanh via hw exp; guards overflow (z>=0 -> t<=1, no NaN).
__device__ __forceinline__ float fast_tanh(float y) {
  float z = fabsf(y);
  float t = __expf(-2.f * z);
  float r = (1.f - t) / (1.f + t);
  return copysignf(r, y);
}
// tanh-form GELU: |err vs erf-GELU| <~ 3e-3, within 0.11 threshold budget.
__device__ __forceinline__ float gelu_f(float x) {
  return 0.5f * x * (1.f + fast_tanh(0.7978845608028654f * (x + 0.044715f * x * x * x)));
}
__device__ __forceinline__ float sigmoid_f(float v) {
  return 1.f / (1.f + __expf(-v));  // __expf(+big)=inf -> 1/inf=0, no NaN
}

__device__ __forceinline__ void async_ld16(const void* g, void* l) {
  using GP = const __attribute__((address_space(1))) uint32_t*;
  using LP = __attribute__((address_space(3))) uint32_t*;
  __builtin_amdgcn_global_load_lds((GP)g, (LP)l, 16, 0, 0);
}

// ---------------------------------------------------------------------------
// ff fp32 -> bf16, 4 elems/thread.
// ---------------------------------------------------------------------------
__global__ void ffb_convert(const float* __restrict__ src, bf16* __restrict__ dst) {
  size_t i = ((size_t)blockIdx.x * 256 + threadIdx.x) * 4;
  float4 v = *reinterpret_cast<const float4*>(src + i);
  ushort4 o;
  o.x = __builtin_bit_cast(unsigned short, f2b(v.x));
  o.y = __builtin_bit_cast(unsigned short, f2b(v.y));
  o.z = __builtin_bit_cast(unsigned short, f2b(v.z));
  o.w = __builtin_bit_cast(unsigned short, f2b(v.w));
  *reinterpret_cast<ushort4*>(dst + i) = o;
}

// ---------------------------------------------------------------------------
// Tiled MFMA GEMM: C[M,N] = act(A[M,K] @ B[K,N] + bias), B as bf16 BT[N][K].
// Tile MTx128 (MT=128 or 64), BK=64, 4 waves 2x(2), wave (MT/2)x64 via
// (MT/32)x4 of 16x16x32. A split at ksplit between A0/A1 (both bf16).
// EPI: 0 bias; 1 bias+GELU; 2 out = ffb + sigmoid(bias+acc)*ctx  (out may
//      alias ffp element-wise: each element read only by its writing thread,
//      read before write).
// ---------------------------------------------------------------------------
template <int EPI, typename OutT, int MT>
__launch_bounds__(256)
__global__ void gemm128(const bf16* A0, const bf16* A1, int ksplit, int lda0, int lda1,
                        const bf16* __restrict__ BT, int K,
                        const float* __restrict__ bias,
                        OutT* out, int ldo,
                        const bf16* ffp, const bf16* ctxp, int ldfc)
{
  constexpr int MIC = MT / 32;  // wave m-frag count (and A staging i-count)
  __shared__ uint16_t smA[MT * 64];
  __shared__ uint16_t smB[128 * 64];
  const int tid = threadIdx.x;
  const int w = tid >> 6;
  const int l = tid & 63;
  const int m0 = blockIdx.x * MT;
  const int n0 = blockIdx.y * 128;
  const int wr = w >> 1, wc = w & 1;
  const int lrow = l & 15, lquad = l >> 4;
  const int rb = w * 8 + (l >> 3);  // staging row within a 32-row group
  const int cpos = l & 7;           // staging 16B-chunk position

  const f32x4 vzero = {0.f, 0.f, 0.f, 0.f};
  f32x4 acc[MIC][4];
#pragma unroll
  for (int i = 0; i < MIC; i++)
#pragma unroll
    for (int j = 0; j < 4; j++) acc[i][j] = vzero;

  for (int k0 = 0; k0 < K; k0 += 64) {
    __syncthreads();
    // LDS (row, c) holds global chunk c ^ (row&7); lane lands at wave-uniform
    // base + lane*16 (global_load_lds constraint).
#pragma unroll
    for (int i = 0; i < MIC; i++) {
      int row = i * 32 + rb;
      int cg = cpos ^ (row & 7);
      int kcol = k0 + cg * 8;
      const bf16* gp = (kcol < ksplit)
                           ? (A0 + (size_t)(m0 + row) * lda0 + kcol)
                           : (A1 + (size_t)(m0 + row) * lda1 + (kcol - ksplit));
      async_ld16(gp, &smA[(i * 32 + w * 8) * 64]);
    }
#pragma unroll
    for (int i = 0; i < 4; i++) {
      int row = i * 32 + rb;
      int cg = cpos ^ (row & 7);
      const bf16* gq = BT + (size_t)(n0 + row) * K + k0 + cg * 8;
      async_ld16(gq, &smB[(i * 32 + w * 8) * 64]);
    }
    __syncthreads();
#pragma unroll
    for (int kk = 0; kk < 2; kk++) {
      bf16x8 af[MIC], bfr[4];
      const int cc = kk * 4 + lquad;
#pragma unroll
      for (int mi = 0; mi < MIC; mi++) {
        int r = wr * (MT / 2) + mi * 16 + lrow;
        af[mi] = *(const bf16x8*)&smA[r * 64 + ((cc ^ (r & 7)) << 3)];
      }
#pragma unroll
      for (int ni = 0; ni < 4; ni++) {
        int r = wc * 64 + ni * 16 + lrow;
        bfr[ni] = *(const bf16x8*)&smB[r * 64 + ((cc ^ (r & 7)) << 3)];
      }
#pragma unroll
      for (int mi = 0; mi < MIC; mi++)
#pragma unroll
        for (int ni = 0; ni < 4; ni++)
          acc[mi][ni] =
              __builtin_amdgcn_mfma_f32_16x16x32_bf16(af[mi], bfr[ni], acc[mi][ni], 0, 0, 0);
    }
  }

  // epilogue: C/D layout col=lane&15, row=(lane>>4)*4+reg
#pragma unroll
  for (int mi = 0; mi < MIC; mi++) {
#pragma unroll
    for (int ni = 0; ni < 4; ni++) {
#pragma unroll
      for (int r = 0; r < 4; r++) {
        int row = m0 + wr * (MT / 2) + mi * 16 + lquad * 4 + r;
        int col = n0 + wc * 64 + ni * 16 + lrow;
        float v = acc[mi][ni][r] + bias[col];
        if (EPI == 1) v = gelu_f(v);
        if (EPI == 2) {
          float gate = sigmoid_f(v);
          size_t fo = (size_t)row * ldfc + col;
          v = b2f(ffp[fo]) + gate * b2f(ctxp[fo]);
        }
        if constexpr (__is_same(OutT, float))
          out[(size_t)row * ldo + col] = v;
        else
          out[(size_t)row * ldo + col] = f2b(v);
      }
    }
  }
}

// ---------------------------------------------------------------------------
// Prep: fp32 weights -> bf16 transposed/folded weights + fp32 folded biases.
// ---------------------------------------------------------------------------
__global__ void prep_kernel(
    const float* __restrict__ Wq_in, const float* __restrict__ bq_in,
    const float* __restrict__ Wq, const float* __restrict__ bq,
    const float* __restrict__ Wk, const float* __restrict__ bk,
    const float* __restrict__ Wv, const float* __restrict__ bv,
    const float* __restrict__ Wo, const float* __restrict__ bo,
    const float* __restrict__ Wc, const float* __restrict__ bc,
    const float* __restrict__ Ws, const float* __restrict__ Wg1,
    const float* __restrict__ Wg2,
    bf16* WKVT, float* BKV, bf16* WQQT, float* BQQ, bf16* WOCT, float* BOC,
    bf16* WST, bf16* WG1T, bf16* WG2T)
{
  int idx = blockIdx.x * 256 + threadIdx.x;
  if (idx < 32768) {  // WKVT[n][k] = (n<128 ? Wk : Wv)[k][n%128]
    int n = idx >> 7, k = idx & 127;
    WKVT[idx] = f2b((n < 128) ? Wk[k * 128 + n] : Wv[k * 128 + (n - 128)]);
    return;
  }
  idx -= 32768;
  if (idx < 256) { BKV[idx] = (idx < 128) ? bk[idx] : bv[idx - 128]; return; }
  idx -= 256;
  if (idx < 131072) {  // WQQT[t][f] = sum_u Wq_in[f][u] * Wq[u][t]
    int t = idx >> 10, f = idx & 1023;
    float s = 0.f;
    for (int u = 0; u < 128; u++) s += Wq_in[f * 128 + u] * Wq[u * 128 + t];
    WQQT[idx] = f2b(s);
    return;
  }
  idx -= 131072;
  if (idx < 128) {  // BQQ[t] = bq_in @ Wq[:,t] + bq[t]
    float s = bq[idx];
    for (int u = 0; u < 128; u++) s += bq_in[u] * Wq[u * 128 + idx];
    BQQ[idx] = s;
    return;
  }
  idx -= 128;
  if (idx < 131072) {  // WOCT[f][d] = sum_t Wo[d][t] * Wc[t][f]
    int f = idx >> 7, d = idx & 127;
    float s = 0.f;
    for (int t = 0; t < 128; t++) s += Wo[d * 128 + t] * Wc[t * 1024 + f];
    WOCT[idx] = f2b(s);
    return;
  }
  idx -= 131072;
  if (idx < 1024) {  // BOC[f] = bo @ Wc[:,f] + bc[f]
    float s = bc[idx];
    for (int t = 0; t < 128; t++) s += bo[t] * Wc[t * 1024 + idx];
    BOC[idx] = s;
    return;
  }
  idx -= 1024;
  if (idx < 393216) { int f = idx / 384, j = idx % 384; WST[idx] = f2b(Ws[j * 1024 + f]); return; }
  idx -= 393216;
  if (idx < 2097152) { int f = idx >> 11, j = idx & 2047; WG1T[idx] = f2b(Wg1[j * 1024 + f]); return; }
  idx -= 2097152;
  if (idx < 1048576) { int f = idx >> 10, j = idx & 1023; WG2T[idx] = f2b(Wg2[j * 1024 + f]); return; }
}

// ---------------------------------------------------------------------------
// Tokens: fp32 in, bf16 TOK out. One block (128 thr) per row.
// ---------------------------------------------------------------------------
__device__ __forceinline__ void emb28(const float* __restrict__ logits,
                                      const float* __restrict__ g,
                                      const float* __restrict__ bb,
                                      const float* __restrict__ W,
                                      const float* __restrict__ wb,
                                      bf16* __restrict__ out, int t,
                                      float* sv, float* sp)
{
  if (t < 28) sv[t] = logits[t];
  __syncthreads();
  float mx = sv[0];
#pragma unroll
  for (int e = 1; e < 28; e++) mx = fmaxf(mx, sv[e]);
  if (t < 28) sp[t] = __expf(sv[t] - mx);
  __syncthreads();
  float sum = 0.f;
#pragma unroll
  for (int e = 0; e < 28; e++) sum += sp[e];
  float inv = 1.f / sum;
  float sp2 = 0.f;
#pragma unroll
  for (int e = 0; e < 28; e++) { float p = sp[e] * inv; sp2 += p * p; }
  const float mean = 1.f / 28.f;  // softmax sums to 1
  float var = sp2 * (1.f / 28.f) - mean * mean;
  float rstd = rsqrtf(var + 1e-5f);
  __syncthreads();
  if (t < 28) sp[t] = (sp[t] * inv - mean) * rstd * g[t] + bb[t];
  __syncthreads();
  float acc = wb[t];
#pragma unroll
  for (int e = 0; e < 28; e++) acc += sp[e] * W[e * 128 + t];
  out[t] = f2b(gelu_f(acc));
  __syncthreads();
}

__global__ void tokens_kernel(
    const float* __restrict__ exl, const float* __restrict__ iml, const float* __restrict__ affv,
    const float* __restrict__ geg, const float* __restrict__ geb,
    const float* __restrict__ Wex, const float* __restrict__ bex,
    const float* __restrict__ gig, const float* __restrict__ gib,
    const float* __restrict__ Wim, const float* __restrict__ bim,
    const float* __restrict__ gag, const float* __restrict__ gab,
    const float* __restrict__ Waf, const float* __restrict__ baf,
    bf16* __restrict__ tokens)
{
  __shared__ float sv[28], sp[28];
  const int b = blockIdx.x, t = threadIdx.x;
  bf16* trow = tokens + (size_t)b * 384;
  emb28(exl + (size_t)b * 28, geg, geb, Wex, bex, trow, t, sv, sp);
  emb28(iml + (size_t)b * 28, gig, gib, Wim, bim, trow + 128, t, sv, sp);
  // affect: LN over 2 values
  float a0 = affv[(size_t)b * 2 + 0];
  float a1 = affv[(size_t)b * 2 + 1];
  float m = 0.5f * (a0 + a1);
  float d0 = a0 - m, d1 = a1 - m;
  float var = 0.5f * (d0 * d0 + d1 * d1);
  float rstd = rsqrtf(var + 1e-5f);
  float l0 = d0 * rstd * gag[0] + gab[0];
  float l1 = d1 * rstd * gag[1] + gab[1];
  float acc = baf[t] + l0 * Waf[t] + l1 * Waf[128 + t];
  trow[256 + t] = f2b(gelu_f(acc));
}

// ---------------------------------------------------------------------------
// Attention: per row, 4 heads x 3 keys; head = t/32, dim = t%32.
// ---------------------------------------------------------------------------
__global__ void attn_kernel(const bf16* __restrict__ qh, const bf16* __restrict__ kvh,
                            bf16* __restrict__ apre, float* __restrict__ attw)
{
  const int b = blockIdx.x, t = threadIdx.x;  // 128 threads
  float q = b2f(qh[(size_t)b * 128 + t]);
  const bf16* kv = kvh + (size_t)b * 3 * 256;
  float s[3], v[3];
#pragma unroll
  for (int i = 0; i < 3; i++) {
    float k = b2f(kv[i * 256 + t]);
    v[i] = b2f(kv[i * 256 + 128 + t]);
    float r = q * k;
#pragma unroll
    for (int off = 16; off > 0; off >>= 1) r += __shfl_down(r, off, 32);
    r = __shfl(r, 0, 32);
    s[i] = r * 0.17677669529663687f;  // 1/sqrt(32)
  }
  float mx = fmaxf(s[0], fmaxf(s[1], s[2]));
  float e0 = __expf(s[0] - mx), e1 = __expf(s[1] - mx), e2 = __expf(s[2] - mx);
  float inv = 1.f / (e0 + e1 + e2);
  float w0 = e0 * inv, w1 = e1 * inv, w2 = e2 * inv;
  apre[(size_t)b * 128 + t] = f2b(w0 * v[0] + w1 * v[1] + w2 * v[2]);
  __shared__ float aw[4][3];
  if ((t & 31) == 0) { int h = t >> 5; aw[h][0] = w0; aw[h][1] = w1; aw[h][2] = w2; }
  __syncthreads();
  if (t < 3)
    attw[(size_t)b * 3 + t] = 0.25f * (aw[0][t] + aw[1][t] + aw[2][t] + aw[3][t]);
}

// ---------------------------------------------------------------------------
// Output LayerNorm over 1024: bf16 in (PRE), fp32 out. One block/row.
// ---------------------------------------------------------------------------
__global__ void ln_out_kernel(const bf16* __restrict__ x, const float* __restrict__ g,
                              const float* __restrict__ bb, float* __restrict__ out)
{
  const int row = blockIdx.x, t = threadIdx.x;
  const bf16* xr = x + (size_t)row * 1024;
  ushort4 u = *reinterpret_cast<const ushort4*>(xr + t * 4);
  float v0 = __uint_as_float((uint32_t)u.x << 16);
  float v1 = __uint_as_float((uint32_t)u.y << 16);
  float v2 = __uint_as_float((uint32_t)u.z << 16);
  float v3 = __uint_as_float((uint32_t)u.w << 16);
  float s = v0 + v1 + v2 + v3;
  float s2 = v0 * v0 + v1 * v1 + v2 * v2 + v3 * v3;
#pragma unroll
  for (int off = 32; off > 0; off >>= 1) {
    s += __shfl_down(s, off, 64);
    s2 += __shfl_down(s2, off, 64);
  }
  __shared__ float ls[4], ls2[4];
  const int w = t >> 6;
  if ((t & 63) == 0) { ls[w] = s; ls2[w] = s2; }
  __syncthreads();
  float S = ls[0] + ls[1] + ls[2] + ls[3];
  float S2 = ls2[0] + ls2[1] + ls2[2] + ls2[3];
  float mean = S * (1.f / 1024.f);
  float var = S2 * (1.f / 1024.f) - mean * mean;
  float rstd = rsqrtf(var + 1e-5f);
  const int c = t * 4;
  float4 o;
  o.x = (v0 - mean) * rstd * g[c + 0] + bb[c + 0];
  o.y = (v1 - mean) * rstd * g[c + 1] + bb[c + 1];
  o.z = (v2 - mean) * rstd * g[c + 2] + bb[c + 2];
  o.w = (v3 - mean) * rstd * g[c + 3] + bb[c + 3];
  *reinterpret_cast<float4*>(out + (size_t)row * 1024 + c) = o;
}

// ---------------------------------------------------------------------------
extern "C" void kernel_launch(void* const* d_in, const int* in_sizes, int n_in,
                              void* d_out, int out_size, void* d_ws, size_t ws_size,
                              hipStream_t stream)
{
  const float* ff   = (const float*)d_in[0];
  const float* exl  = (const float*)d_in[1];
  const float* iml  = (const float*)d_in[2];
  const float* affv = (const float*)d_in[3];
  const float* geg = (const float*)d_in[4],  *geb = (const float*)d_in[5];
  const float* Wex = (const float*)d_in[6],  *bex = (const float*)d_in[7];
  const float* gig = (const float*)d_in[8],  *gib = (const float*)d_in[9];
  const float* Wim = (const float*)d_in[10], *bim = (const float*)d_in[11];
  const float* gag = (const float*)d_in[12], *gab = (const float*)d_in[13];
  const float* Waf = (const float*)d_in[14], *baf = (const float*)d_in[15];
  const float* Wq_in = (const float*)d_in[16], *bq_in = (const float*)d_in[17];
  const float* Wq = (const float*)d_in[18], *bq = (const float*)d_in[19];
  const float* Wk = (const float*)d_in[20], *bk = (const float*)d_in[21];
  const float* Wv = (const float*)d_in[22], *bv = (const float*)d_in[23];
  const float* Wo = (const float*)d_in[24], *bo = (const float*)d_in[25];
  const float* Wc = (const float*)d_in[26], *bc = (const float*)d_in[27];
  const float* Ws = (const float*)d_in[28], *bs = (const float*)d_in[29];
  const float* Wg1 = (const float*)d_in[30], *bg1 = (const float*)d_in[31];
  const float* Wg2 = (const float*)d_in[32], *bg2 = (const float*)d_in[33];
  const float* lng = (const float*)d_in[34], *lnb = (const float*)d_in[35];

  // workspace layout (bytes); peak = 62,199,296 (~59.3 MB)
  char* ws = (char*)d_ws;
  bf16*  WKVT = (bf16*)(ws + 0);         //  32768 el bf16
  float* BKV  = (float*)(ws + 65536);    //    256 el f32
  bf16*  WQQT = (bf16*)(ws + 66560);     // 131072 el bf16
  float* BQQ  = (float*)(ws + 328704);   //    128 el f32
  bf16*  WOCT = (bf16*)(ws + 329216);    // 131072 el bf16
  float* BOC  = (float*)(ws + 591360);   //   1024 el f32
  bf16*  WST  = (bf16*)(ws + 595456);    // 393216 el bf16
  bf16*  WG1T = (bf16*)(ws + 1381888);   // 2097152 el bf16
  bf16*  WG2T = (bf16*)(ws + 5576192);   // 1048576 el bf16
  bf16*  FFB  = (bf16*)(ws + 7673344);   // B*1024 (live: convert..G6)
  bf16*  PRE  = (bf16*)(ws + 7673344);   // B*1024, aliases FFB elem-wise (G6..ln)
  bf16*  TOK  = (bf16*)(ws + 41227776);  // B*384  (live: tokens..G4)
  bf16*  QH   = (bf16*)(ws + 53810688);  // B*128  (live: G1..attn)
  bf16*  APRE = (bf16*)(ws + 58004992);  // B*128  (live: attn..G3)

  float* outp = (float*)d_out;
  float* out_refined = outp;             // B*1024 f32; hosts CTX bf16 G3..G6
  float* out_attw    = outp + 16777216;  // B*3 f32
  float* out_summary = outp + 16826368;  // B*1024 f32; hosts KVH bf16 G2..attn, GATEH bf16 G5..G6
  bf16* CTX   = (bf16*)out_refined;
  bf16* KVH   = (bf16*)out_summary;
  bf16* GATEH = (bf16*)out_summary;

  ffb_convert<<<16384, 256, 0, stream>>>(ff, FFB);
  prep_kernel<<<14982, 256, 0, stream>>>(Wq_in, bq_in, Wq, bq, Wk, bk, Wv, bv,
                                         Wo, bo, Wc, bc, Ws, Wg1, Wg2,
                                         WKVT, BKV, WQQT, BQQ, WOCT, BOC,
                                         WST, WG1T, WG2T);
  tokens_kernel<<<16384, 128, 0, stream>>>(exl, iml, affv, geg, geb, Wex, bex,
                                           gig, gib, Wim, bim, gag, gab, Waf, baf, TOK);
  // G1: qh = FFB @ WqqT + bqq  (M=16384, K=1024, N=128), 64-row tiles
  gemm128<0, bf16, 64><<<dim3(256, 1), 256, 0, stream>>>(FFB, FFB, 1024, 1024, 1024, WQQT, 1024,
                                                         BQQ, QH, 128, nullptr, nullptr, 0);
  // G2: kvh = TOK @ [Wk|Wv]T  (M=49152, K=128, N=256) -> summary slot
  gemm128<0, bf16, 128><<<dim3(384, 2), 256, 0, stream>>>(TOK, TOK, 128, 128, 128, WKVT, 128,
                                                          BKV, KVH, 256, nullptr, nullptr, 0);
  attn_kernel<<<16384, 128, 0, stream>>>(QH, KVH, APRE, out_attw);
  // G3: ctx = APRE @ WocT + boc  (M=16384, K=128, N=1024) -> refined slot (bf16)
  gemm128<0, bf16, 128><<<dim3(128, 8), 256, 0, stream>>>(APRE, APRE, 128, 128, 128, WOCT, 128,
                                                          BOC, CTX, 1024, nullptr, nullptr, 0);
  // G5: gate_h = gelu([FFB|CTX] @ Wg1T + bg1)  (K=2048) -> summary slot (kvh dead)
  gemm128<1, bf16, 128><<<dim3(128, 8), 256, 0, stream>>>(FFB, CTX, 1024, 1024, 1024, WG1T, 2048,
                                                          bg1, GATEH, 1024, nullptr, nullptr, 0);
  // G6: pre = FFB + sigmoid(gate_h @ Wg2T + bg2) * ctx -> PRE (elem-wise alias of FFB)
  gemm128<2, bf16, 128><<<dim3(128, 8), 256, 0, stream>>>(GATEH, GATEH, 1024, 1024, 1024, WG2T, 1024,
                                                          bg2, PRE, 1024, FFB, CTX, 1024);
  // G4: summary = gelu(TOK @ WsT + bs)  (K=384) -> summary fp32 final (gateh dead)
  gemm128<1, float, 128><<<dim3(128, 8), 256, 0, stream>>>(TOK, TOK, 384, 384, 384, WST, 384,
                                                           bs, out_summary, 1024, nullptr, nullptr, 0);
  // final LN: PRE bf16 -> refined fp32 (ctx dead)
  ln_out_kernel<<<16384, 256, 0, stream>>>(PRE, lng, lnb, out_refined);
}